// Round 1
// baseline (8041.213 us; speedup 1.0000x reference)
//
#include <hip/hip_runtime.h>

#define HW 256
#define NPIX (HW * HW)  // 65536

// ---------------------------------------------------------------------------
// Direct 3x3 conv, stride 1, SAME zero pad. Tile 32x8 pixels, block 256.
// One thread = one pixel, all 64 output channels accumulated in registers.
// Weights are block-uniform -> scalar loads (SGPR operand of v_fma).
// Input staged in LDS in CHUNK-channel slices (34x10 halo tile each).
// ---------------------------------------------------------------------------
template <int CIN, int CHUNK, bool RELU, bool RESID>
__global__ __launch_bounds__(256, 3) void conv3x3_k(
    const float* __restrict__ in, const float* __restrict__ w,
    const float* __restrict__ bias, const float* __restrict__ resid,
    float* __restrict__ out) {
  __shared__ float xs[CHUNK][10][34];

  const int tid = threadIdx.x;
  const int px = tid & 31;
  const int py = tid >> 5;
  const int tx0 = blockIdx.x * 32;
  const int ty0 = blockIdx.y * 8;
  const int b = blockIdx.z;

  float acc[64];
#pragma unroll
  for (int oc = 0; oc < 64; ++oc) acc[oc] = bias[oc];

  for (int ic0 = 0; ic0 < CIN; ic0 += CHUNK) {
    __syncthreads();
    // cooperative stage: CHUNK channels of a 34x10 halo tile
    for (int e = tid; e < CHUNK * 340; e += 256) {
      int ch = e / 340;
      int rem = e - ch * 340;
      int r = rem / 34;
      int c = rem - r * 34;
      int gy = ty0 - 1 + r;
      int gx = tx0 - 1 + c;
      float v = 0.f;
      if ((unsigned)gy < HW && (unsigned)gx < HW)
        v = in[((b * CIN + ic0 + ch) * HW + gy) * HW + gx];
      xs[ch][r][c] = v;
    }
    __syncthreads();

    for (int c = 0; c < CHUNK; ++c) {
      float xv[9];
#pragma unroll
      for (int t = 0; t < 9; ++t) xv[t] = xs[c][py + t / 3][px + t % 3];
      const float* wp = &w[(ic0 + c) * 9];  // + oc*CIN*9 + t
#pragma unroll
      for (int oc = 0; oc < 64; ++oc) {
        float a = acc[oc];
#pragma unroll
        for (int t = 0; t < 9; ++t) a = fmaf(xv[t], wp[oc * CIN * 9 + t], a);
        acc[oc] = a;
      }
    }
  }

  const int gy = ty0 + py;
  const int gx = tx0 + px;
  const int pix = gy * HW + gx;
#pragma unroll
  for (int oc = 0; oc < 64; ++oc) {
    float v = acc[oc];
    if (RELU) v = fmaxf(v, 0.f);
    int idx = (b * 64 + oc) * NPIX + pix;
    if (RESID) v += resid[idx];
    out[idx] = v;
  }
}

// ---------------------------------------------------------------------------
// Fused out-conv (64 -> 225) + abs-softmax kernel-conv, online-softmax style.
// Tile 16x8 pixels, block 128 (one thread per pixel).
// LDS: x halo tile [64][10][18] (46 KB) + data halo tile [3][22][30] (7.9 KB).
// 225 channels processed in 25 groups of 9; per group: 576 LDS reads,
// 5184 scalar-weight FMAs, then 9 online-softmax updates.
// ---------------------------------------------------------------------------
__global__ __launch_bounds__(128, 2) void out_kc_k(
    const float* __restrict__ x, const float* __restrict__ w_out,
    const float* __restrict__ b_out, const float* __restrict__ data,
    float* __restrict__ pred) {
  __shared__ float xs[64][10][18];
  __shared__ float dsh[3][22][30];

  const int tid = threadIdx.x;
  const int px = tid & 15;
  const int py = tid >> 4;
  const int tx0 = blockIdx.x * 16;
  const int ty0 = blockIdx.y * 8;
  const int b = blockIdx.z;

  // stage x: 64 channels of 18x10 halo
  for (int e = tid; e < 64 * 180; e += 128) {
    int ch = e / 180;
    int rem = e - ch * 180;
    int r = rem / 18;
    int c = rem - r * 18;
    int gy = ty0 - 1 + r;
    int gx = tx0 - 1 + c;
    float v = 0.f;
    if ((unsigned)gy < HW && (unsigned)gx < HW)
      v = x[((b * 64 + ch) * HW + gy) * HW + gx];
    xs[ch][r][c] = v;
  }
  // stage data: 3 channels of 30x22 halo (pad 7 each side)
  for (int e = tid; e < 3 * 660; e += 128) {
    int ch = e / 660;
    int rem = e - ch * 660;
    int r = rem / 30;
    int c = rem - r * 30;
    int gy = ty0 - 7 + r;
    int gx = tx0 - 7 + c;
    float v = 0.f;
    if ((unsigned)gy < HW && (unsigned)gx < HW)
      v = data[((b * 3 + ch) * HW + gy) * HW + gx];
    dsh[ch][r][c] = v;
  }
  __syncthreads();

  float m = -1e30f, l = 0.f;
  float pr0 = 0.f, pr1 = 0.f, pr2 = 0.f;

  for (int g = 0; g < 25; ++g) {
    float core[9];
#pragma unroll
    for (int q = 0; q < 9; ++q) core[q] = b_out[g * 9 + q];
    for (int ic = 0; ic < 64; ++ic) {
#pragma unroll
      for (int t = 0; t < 9; ++t) {
        float xv = xs[ic][py + t / 3][px + t % 3];
#pragma unroll
        for (int q = 0; q < 9; ++q)
          core[q] = fmaf(xv, w_out[((g * 9 + q) * 64 + ic) * 9 + t], core[q]);
      }
    }
#pragma unroll
    for (int q = 0; q < 9; ++q) {
      int c = g * 9 + q;
      float a = fabsf(core[q]);
      float mn = fmaxf(m, a);
      float scale = __expf(m - mn);  // m=-1e30 first iter -> exp(-inf)=0
      float e = __expf(a - mn);
      int di = c / 15, dj = c - (c / 15) * 15;
      l = l * scale + e;
      pr0 = pr0 * scale + e * dsh[0][py + di][px + dj];
      pr1 = pr1 * scale + e * dsh[1][py + di][px + dj];
      pr2 = pr2 * scale + e * dsh[2][py + di][px + dj];
      m = mn;
    }
  }

  const float inv = 1.f / l;
  const int pix = (ty0 + py) * HW + (tx0 + px);
  pred[(b * 3 + 0) * NPIX + pix] = pr0 * inv;
  pred[(b * 3 + 1) * NPIX + pix] = pr1 * inv;
  pred[(b * 3 + 2) * NPIX + pix] = pr2 * inv;
}

// ---------------------------------------------------------------------------
// data -> d_out[0 : 786432] verbatim copy (float4)
// ---------------------------------------------------------------------------
__global__ void copy_k(const float4* __restrict__ src, float4* __restrict__ dst,
                       int n4) {
  int i = blockIdx.x * blockDim.x + threadIdx.x;
  if (i < n4) dst[i] = src[i];
}

extern "C" void kernel_launch(void* const* d_in, const int* in_sizes, int n_in,
                              void* d_out, int out_size, void* d_ws,
                              size_t ws_size, hipStream_t stream) {
  const float* data_with_est = (const float*)d_in[0];
  const float* data = (const float*)d_in[1];
  const float* w_first = (const float*)d_in[2];
  const float* b_first = (const float*)d_in[3];
  const float* w1a = (const float*)d_in[4];
  const float* b1a = (const float*)d_in[5];
  const float* w1b = (const float*)d_in[6];
  const float* b1b = (const float*)d_in[7];
  const float* w2a = (const float*)d_in[8];
  const float* b2a = (const float*)d_in[9];
  const float* w2b = (const float*)d_in[10];
  const float* b2b = (const float*)d_in[11];
  const float* w3a = (const float*)d_in[12];
  const float* b3a = (const float*)d_in[13];
  const float* w3b = (const float*)d_in[14];
  const float* b3b = (const float*)d_in[15];
  const float* w_out = (const float*)d_in[16];
  const float* b_out = (const float*)d_in[17];

  float* out = (float*)d_out;
  float* pred = out + 4 * 3 * NPIX;  // second tuple element

  // workspace: x, y feature maps [4,64,256,256] fp32 (64 MiB each)
  float* x = (float*)d_ws;
  float* y = x + 4 * 64 * NPIX;

  dim3 cgrid(HW / 32, HW / 8, 4);
  dim3 cblk(256);

  // first conv 6->64
  conv3x3_k<6, 6, false, false>
      <<<cgrid, cblk, 0, stream>>>(data_with_est, w_first, b_first, nullptr, x);

  // residual block 1
  conv3x3_k<64, 8, true, false>
      <<<cgrid, cblk, 0, stream>>>(x, w1a, b1a, nullptr, y);
  conv3x3_k<64, 8, false, true>
      <<<cgrid, cblk, 0, stream>>>(y, w1b, b1b, x, x);
  // residual block 2
  conv3x3_k<64, 8, true, false>
      <<<cgrid, cblk, 0, stream>>>(x, w2a, b2a, nullptr, y);
  conv3x3_k<64, 8, false, true>
      <<<cgrid, cblk, 0, stream>>>(y, w2b, b2b, x, x);
  // residual block 3
  conv3x3_k<64, 8, true, false>
      <<<cgrid, cblk, 0, stream>>>(x, w3a, b3a, nullptr, y);
  conv3x3_k<64, 8, false, true>
      <<<cgrid, cblk, 0, stream>>>(y, w3b, b3b, x, x);

  // fused out-conv (64->225) + abs-softmax kernel-conv
  dim3 ogrid(HW / 16, HW / 8, 4);
  out_kc_k<<<ogrid, dim3(128), 0, stream>>>(x, w_out, b_out, data, pred);

  // data passthrough (first tuple element)
  int n4 = 4 * 3 * NPIX / 4;
  copy_k<<<(n4 + 255) / 256, 256, 0, stream>>>((const float4*)data,
                                               (float4*)out, n4);
}

// Round 2
// 903.393 us; speedup vs baseline: 8.9011x; 8.9011x over previous
//
#include <hip/hip_runtime.h>

#define HW 256
#define NPIX (HW * HW)  // 65536

using short8 = __attribute__((ext_vector_type(8))) short;
using short4v = __attribute__((ext_vector_type(4))) short;
using f32x4 = __attribute__((ext_vector_type(4))) float;

// ---- bf16 helpers (raw ushort bits) ----
static __device__ __forceinline__ ushort f2bf(float f) {
  unsigned u = __float_as_uint(f);
  unsigned r = (u + 0x7FFFu + ((u >> 16) & 1u)) >> 16;  // RNE
  return (ushort)r;
}
static __device__ __forceinline__ float bf2f(ushort u) {
  return __uint_as_float(((unsigned)u) << 16);
}

// ---------------------------------------------------------------------------
// pack data_with_est [4,6,256,256] fp32 NCHW -> xp [4,65536,8] bf16 (ch 6,7=0)
// ---------------------------------------------------------------------------
__global__ void pack_in_k(const float* __restrict__ din, ushort* __restrict__ xp) {
  int i = blockIdx.x * 256 + threadIdx.x;  // 0 .. 262143
  int b = i >> 16;
  int px = i & 65535;
  short8 v;
#pragma unroll
  for (int z = 0; z < 8; ++z) v[z] = 0;
#pragma unroll
  for (int ic = 0; ic < 6; ++ic)
    v[ic] = (short)f2bf(din[(b * 6 + ic) * NPIX + px]);
  *(short8*)&xp[i * 8] = v;
}

// ---------------------------------------------------------------------------
// pack conv weights [OC, CIN, 3, 3] fp32 -> wp [OCPAD][TPAD*CPAD] bf16
// k = t*CPAD + ic ; zero rows/cols for padding
// ---------------------------------------------------------------------------
__global__ void pack_w_k(const float* __restrict__ w, ushort* __restrict__ wp,
                         int OC, int CIN, int CPAD, int TPAD, int total) {
  int i = blockIdx.x * 256 + threadIdx.x;
  if (i >= total) return;
  int K = TPAD * CPAD;
  int oc = i / K;
  int r = i - oc * K;
  int t = r / CPAD;
  int ic = r - t * CPAD;
  float v = 0.f;
  if (oc < OC && ic < CIN && t < 9) v = w[(oc * CIN + ic) * 9 + t];
  wp[i] = f2bf(v);
}

// ---------------------------------------------------------------------------
// Implicit-GEMM 3x3 conv via bf16 MFMA 16x16x32.
// In/out NHWC bf16 ([B][H][W][C] / [B][H][W][64]). Block 256 = 4 waves.
// Pixel tile: 1 row x 128 cols; each wave: all 64 oc x 32 px (4 m x 2 n tiles).
// LDS: halo row-tile [3][130][C] bf16, chunk-XOR-swizzled for bank safety.
// A-fragments (packed weights) streamed from global (L2-resident, 73 KB).
// ---------------------------------------------------------------------------
template <int C, int KS, bool RELU, bool RESID>
__global__ __launch_bounds__(256) void conv_mfma_k(
    const ushort* __restrict__ in, const ushort* __restrict__ wp,
    const float* __restrict__ bias, const ushort* __restrict__ resid,
    ushort* __restrict__ out) {
  constexpr int SWM = (C == 64) ? 7 : 0;  // swizzle mask on 8-ch chunk idx
  constexpr int CV = C / 8;
  __shared__ __align__(16) ushort xs[3][130][C];

  const int tid = threadIdx.x;
  const int wave = tid >> 6, lane = tid & 63;
  const int quad = lane >> 4, l15 = lane & 15;
  const int x0 = blockIdx.x * 128, y = blockIdx.y, b = blockIdx.z;

  // stage halo tile (zero-fill OOB), 16B vector loads, coalesced
  for (int i = tid; i < 3 * 130 * CV; i += 256) {
    int ch8 = i % CV;
    int rem = i / CV;
    int col = rem % 130;
    int row = rem / 130;
    int gy = y - 1 + row, gx = x0 - 1 + col;
    short8 v;
#pragma unroll
    for (int z = 0; z < 8; ++z) v[z] = 0;
    if ((unsigned)gy < (unsigned)HW && (unsigned)gx < (unsigned)HW)
      v = *(const short8*)&in[(((b << 8) + gy) * HW + gx) * C + ch8 * 8];
    *(short8*)&xs[row][col][(ch8 ^ (col & SWM)) * 8] = v;
  }
  __syncthreads();

  f32x4 acc[4][2];
#pragma unroll
  for (int mt = 0; mt < 4; ++mt)
#pragma unroll
    for (int nt = 0; nt < 2; ++nt)
#pragma unroll
      for (int r = 0; r < 4; ++r) acc[mt][nt][r] = 0.f;

  const int xl0 = wave * 32 + l15;  // local pixel of n-tile 0

  for (int ks = 0; ks < KS; ++ks) {
    int t, chunk;
    if (C == 64) {
      t = ks >> 1;                       // tap (uniform)
      chunk = ((ks & 1) << 2) + quad;    // 8-ch chunk 0..7
    } else {
      t = ks * 4 + quad;                 // tap (per-quad)
      if (t > 8) t = 8;                  // dummy taps: A rows are zero
      chunk = 0;
    }
    int dy = t / 3, dx = t - (t / 3) * 3;

    short8 bfrag[2];
#pragma unroll
    for (int nt = 0; nt < 2; ++nt) {
      int c = xl0 + nt * 16 + dx;
      bfrag[nt] = *(const short8*)&xs[dy][c][(chunk ^ (c & SWM)) * 8];
    }
    short8 afrag[4];
#pragma unroll
    for (int mt = 0; mt < 4; ++mt)
      afrag[mt] =
          *(const short8*)&wp[(mt * 16 + l15) * (KS * 32) + ks * 32 + quad * 8];
#pragma unroll
    for (int mt = 0; mt < 4; ++mt)
#pragma unroll
      for (int nt = 0; nt < 2; ++nt)
        acc[mt][nt] = __builtin_amdgcn_mfma_f32_16x16x32_bf16(
            afrag[mt], bfrag[nt], acc[mt][nt], 0, 0, 0);
  }

  // epilogue: C/D layout col=lane&15 (pixel), row=quad*4+reg (oc)
#pragma unroll
  for (int mt = 0; mt < 4; ++mt) {
    const float4 bb = *(const float4*)&bias[mt * 16 + quad * 4];
#pragma unroll
    for (int nt = 0; nt < 2; ++nt) {
      int px = x0 + wave * 32 + nt * 16 + l15;
      size_t base =
          ((size_t)((b << 8) + y) * HW + px) * 64 + mt * 16 + quad * 4;
      float v0 = acc[mt][nt][0] + bb.x;
      float v1 = acc[mt][nt][1] + bb.y;
      float v2 = acc[mt][nt][2] + bb.z;
      float v3 = acc[mt][nt][3] + bb.w;
      if (RELU) {
        v0 = fmaxf(v0, 0.f); v1 = fmaxf(v1, 0.f);
        v2 = fmaxf(v2, 0.f); v3 = fmaxf(v3, 0.f);
      }
      if (RESID) {
        short4v rv = *(const short4v*)&resid[base];
        v0 += bf2f((ushort)rv[0]); v1 += bf2f((ushort)rv[1]);
        v2 += bf2f((ushort)rv[2]); v3 += bf2f((ushort)rv[3]);
      }
      short4v o;
      o[0] = (short)f2bf(v0); o[1] = (short)f2bf(v1);
      o[2] = (short)f2bf(v2); o[3] = (short)f2bf(v3);
      *(short4v*)&out[base] = o;
    }
  }
}

// ---------------------------------------------------------------------------
// Fused out-conv (64->225, padded to 256) + abs-softmax + 15x15 kernel-conv.
// Block 256 = 4 waves over a 64-px row tile. Each wave computes its own 64
// output channels for ALL 64 px (4 m x 4 n tiles). |core+bias| is exchanged
// via fp16 LDS (aliasing the x tile), then per-pixel softmax + tap-weighted
// sum of `data` with shfl reductions across the 4 channel-quarters.
// ---------------------------------------------------------------------------
__global__ __launch_bounds__(256) void out_kc_k(
    const ushort* __restrict__ x, const ushort* __restrict__ wpo,
    const float* __restrict__ b_out, const float* __restrict__ data,
    float* __restrict__ pred) {
  __shared__ __align__(16) char regA[64 * 258 * 2];  // xs (25344B) | core (33024B)
  __shared__ float dsh[3][15][78];
  __shared__ float bsh[256];
  ushort(*xs)[66][64] = (ushort(*)[66][64])regA;
  _Float16* coreSh = (_Float16*)regA;  // [64][258]

  const int tid = threadIdx.x;
  const int wave = tid >> 6, lane = tid & 63;
  const int quad = lane >> 4, l15 = lane & 15;
  const int x0 = blockIdx.x * 64, y = blockIdx.y, b = blockIdx.z;

  bsh[tid] = (tid < 225) ? b_out[tid] : 0.f;

  // stage x halo tile [3][66][64], swizzled
  for (int i = tid; i < 3 * 66 * 8; i += 256) {
    int ch8 = i & 7;
    int rem = i >> 3;
    int col = rem % 66;
    int row = rem / 66;
    int gy = y - 1 + row, gx = x0 - 1 + col;
    short8 v;
#pragma unroll
    for (int z = 0; z < 8; ++z) v[z] = 0;
    if ((unsigned)gy < (unsigned)HW && (unsigned)gx < (unsigned)HW)
      v = *(const short8*)&x[(((b << 8) + gy) * HW + gx) * 64 + ch8 * 8];
    *(short8*)&xs[row][col][(ch8 ^ (col & 7)) * 8] = v;
  }
  // stage data halo [3][15][78] fp32 (pad 7, zero-fill)
  for (int i = tid; i < 3 * 15 * 78; i += 256) {
    int col = i / 1170;
    int rem = i - col * 1170;
    int r = rem / 78;
    int cc = rem - r * 78;
    int gy = y - 7 + r, gx = x0 - 7 + cc;
    float v = 0.f;
    if ((unsigned)gy < (unsigned)HW && (unsigned)gx < (unsigned)HW)
      v = data[((b * 3 + col) << 16) + (gy << 8) + gx];
    dsh[col][r][cc] = v;
  }
  __syncthreads();

  // K loop: wave computes channels [wave*64, wave*64+64) for px 0..63
  f32x4 acc[4][4];
#pragma unroll
  for (int mt = 0; mt < 4; ++mt)
#pragma unroll
    for (int nt = 0; nt < 4; ++nt)
#pragma unroll
      for (int r = 0; r < 4; ++r) acc[mt][nt][r] = 0.f;

  for (int ks = 0; ks < 18; ++ks) {
    int t = ks >> 1;
    int dy = t / 3, dx = t - (t / 3) * 3;
    int chunk = ((ks & 1) << 2) + quad;
    short8 afrag[4];
#pragma unroll
    for (int mt = 0; mt < 4; ++mt)
      afrag[mt] = *(const short8*)&wpo[(wave * 64 + mt * 16 + l15) * 576 +
                                       ks * 32 + quad * 8];
#pragma unroll
    for (int nt = 0; nt < 4; ++nt) {
      int c = nt * 16 + l15 + dx;
      short8 bfrag = *(const short8*)&xs[dy][c][(chunk ^ (c & 7)) * 8];
#pragma unroll
      for (int mt = 0; mt < 4; ++mt)
        acc[mt][nt] = __builtin_amdgcn_mfma_f32_16x16x32_bf16(
            afrag[mt], bfrag, acc[mt][nt], 0, 0, 0);
    }
  }
  __syncthreads();  // retire xs reads before aliasing as coreSh

  // producer: write |core + bias| (masked channels -> -1e4) as fp16
#pragma unroll
  for (int mt = 0; mt < 4; ++mt) {
    int c0 = wave * 64 + mt * 16 + quad * 4;
#pragma unroll
    for (int nt = 0; nt < 4; ++nt) {
      int px = nt * 16 + l15;
#pragma unroll
      for (int r = 0; r < 4; ++r) {
        int c = c0 + r;
        float a = acc[mt][nt][r] + bsh[c];
        a = (c < 225) ? fabsf(a) : -1e4f;
        coreSh[px * 258 + c] = (_Float16)a;
      }
    }
  }
  __syncthreads();

  // consumer: lane -> (px = wave*16 + l15, channel quarter = quad)
  const int px = wave * 16 + l15;
  const int cbase = quad * 64;
  float m = -1e5f;
#pragma unroll 8
  for (int j = 0; j < 64; ++j) {
    float a = (float)coreSh[px * 258 + cbase + j];
    m = fmaxf(m, a);
  }
  m = fmaxf(m, __shfl_xor(m, 16));
  m = fmaxf(m, __shfl_xor(m, 32));

  float l = 0.f, p0 = 0.f, p1 = 0.f, p2 = 0.f;
  for (int j = 0; j < 64; ++j) {
    int c = cbase + j;
    float a = (float)coreSh[px * 258 + c];
    float e = __expf(a - m);  // masked channels underflow to exactly 0
    l += e;
    if (c < 225) {
      int di = c / 15;
      int dj = c - di * 15;
      p0 += e * dsh[0][di][px + dj];
      p1 += e * dsh[1][di][px + dj];
      p2 += e * dsh[2][di][px + dj];
    }
  }
  l += __shfl_xor(l, 16);  l += __shfl_xor(l, 32);
  p0 += __shfl_xor(p0, 16); p0 += __shfl_xor(p0, 32);
  p1 += __shfl_xor(p1, 16); p1 += __shfl_xor(p1, 32);
  p2 += __shfl_xor(p2, 16); p2 += __shfl_xor(p2, 32);

  if (quad == 0) {
    float inv = 1.f / l;
    int pix = (y << 8) + x0 + px;
    pred[((b * 3 + 0) << 16) + pix] = p0 * inv;
    pred[((b * 3 + 1) << 16) + pix] = p1 * inv;
    pred[((b * 3 + 2) << 16) + pix] = p2 * inv;
  }
}

// ---------------------------------------------------------------------------
// data -> d_out[0 : 786432] verbatim copy (float4)
// ---------------------------------------------------------------------------
__global__ void copy_k(const float4* __restrict__ src, float4* __restrict__ dst,
                       int n4) {
  int i = blockIdx.x * blockDim.x + threadIdx.x;
  if (i < n4) dst[i] = src[i];
}

extern "C" void kernel_launch(void* const* d_in, const int* in_sizes, int n_in,
                              void* d_out, int out_size, void* d_ws,
                              size_t ws_size, hipStream_t stream) {
  const float* data_with_est = (const float*)d_in[0];
  const float* data = (const float*)d_in[1];
  const float* w_first = (const float*)d_in[2];
  const float* b_first = (const float*)d_in[3];
  const float* wa[3] = {(const float*)d_in[4], (const float*)d_in[8],
                        (const float*)d_in[12]};
  const float* ba[3] = {(const float*)d_in[5], (const float*)d_in[9],
                        (const float*)d_in[13]};
  const float* wb[3] = {(const float*)d_in[6], (const float*)d_in[10],
                        (const float*)d_in[14]};
  const float* bb[3] = {(const float*)d_in[7], (const float*)d_in[11],
                        (const float*)d_in[15]};
  const float* w_out = (const float*)d_in[16];
  const float* b_out = (const float*)d_in[17];

  float* out = (float*)d_out;
  float* pred = out + 4 * 3 * NPIX;

  // workspace layout (ushort units)
  ushort* x = (ushort*)d_ws;            // 4*65536*64
  ushort* y = x + 4 * NPIX * 64;        // 4*65536*64
  ushort* xp = y + 4 * NPIX * 64;       // 4*65536*8
  ushort* Wp1 = xp + 4 * NPIX * 8;      // 64*96
  ushort* Wpr = Wp1 + 64 * 96;          // 6*36864
  ushort* Wpo = Wpr + 6 * 36864;        // 256*576

  // packs
  pack_in_k<<<1024, 256, 0, stream>>>(data_with_est, xp);
  pack_w_k<<<24, 256, 0, stream>>>(w_first, Wp1, 64, 6, 8, 12, 64 * 96);
  for (int i = 0; i < 3; ++i) {
    pack_w_k<<<144, 256, 0, stream>>>(wa[i], Wpr + (2 * i) * 36864, 64, 64, 64,
                                      9, 36864);
    pack_w_k<<<144, 256, 0, stream>>>(wb[i], Wpr + (2 * i + 1) * 36864, 64, 64,
                                      64, 9, 36864);
  }
  pack_w_k<<<576, 256, 0, stream>>>(w_out, Wpo, 225, 64, 64, 9, 256 * 576);

  dim3 cgrid(2, HW, 4), cblk(256);
  // first conv 6->64 (C padded to 8, K padded to 96)
  conv_mfma_k<8, 3, false, false>
      <<<cgrid, cblk, 0, stream>>>(xp, Wp1, b_first, nullptr, x);
  // 3 residual blocks
  for (int i = 0; i < 3; ++i) {
    conv_mfma_k<64, 18, true, false><<<cgrid, cblk, 0, stream>>>(
        x, Wpr + (2 * i) * 36864, ba[i], nullptr, y);
    conv_mfma_k<64, 18, false, true><<<cgrid, cblk, 0, stream>>>(
        y, Wpr + (2 * i + 1) * 36864, bb[i], x, x);
  }
  // fused out-conv + softmax + kernel-conv
  out_kc_k<<<dim3(4, HW, 4), 256, 0, stream>>>(x, Wpo, b_out, data, pred);
  // data passthrough
  int n4 = 4 * 3 * NPIX / 4;
  copy_k<<<(n4 + 255) / 256, 256, 0, stream>>>((const float4*)data,
                                               (float4*)out, n4);
}

// Round 3
// 750.635 us; speedup vs baseline: 10.7126x; 1.2035x over previous
//
#include <hip/hip_runtime.h>

#define HW 256
#define PW 258              // padded width/height
#define PP (PW * PW)        // padded pixels per image
#define NPIX (HW * HW)

using short8 = __attribute__((ext_vector_type(8))) short;
using short4v = __attribute__((ext_vector_type(4))) short;
using f32x4 = __attribute__((ext_vector_type(4))) float;
using h4 = __attribute__((ext_vector_type(4))) _Float16;
using h8 = __attribute__((ext_vector_type(8))) _Float16;

// async global->LDS, 16B per lane; LDS dest = wave-uniform base + lane*16
#define GLD_LDS(g, l)                                                  \
  __builtin_amdgcn_global_load_lds(                                    \
      (const __attribute__((address_space(1))) void*)(g),              \
      (__attribute__((address_space(3))) void*)(l), 16, 0, 0)

static __device__ __forceinline__ ushort f2bf(float f) {
  unsigned u = __float_as_uint(f);
  unsigned r = (u + 0x7FFFu + ((u >> 16) & 1u)) >> 16;  // RNE
  return (ushort)r;
}
static __device__ __forceinline__ float bf2f(ushort u) {
  return __uint_as_float(((unsigned)u) << 16);
}

// ---------------------------------------------------------------------------
// pack data_with_est [4,6,256,256] fp32 NCHW -> xp padded [4][258][258][8] bf16
// (interior only; halo zeroed by zero_halo_k)
// ---------------------------------------------------------------------------
__global__ void pack_in_k(const float* __restrict__ din, ushort* __restrict__ xp) {
  int i = blockIdx.x * 256 + threadIdx.x;  // 0 .. 262143
  int b = i >> 16;
  int px = i & 65535;
  int y = px >> 8, x = px & 255;
  short8 v;
#pragma unroll
  for (int z = 0; z < 8; ++z) v[z] = 0;
#pragma unroll
  for (int ic = 0; ic < 6; ++ic)
    v[ic] = (short)f2bf(din[(b * 6 + ic) * NPIX + px]);
  *(short8*)&xp[((size_t)b * PP + (size_t)(y + 1) * PW + (x + 1)) * 8] = v;
}

// ---------------------------------------------------------------------------
// zero the 1-px halo ring of x, y (64ch) and xp (8ch) padded buffers
// ---------------------------------------------------------------------------
__global__ void zero_halo_k(ushort* __restrict__ x, ushort* __restrict__ y,
                            ushort* __restrict__ xp) {
  int i = blockIdx.x * 256 + threadIdx.x;
  if (i >= 4 * 1028) return;
  int b = i / 1028;
  int h = i - b * 1028;
  int py, px;
  if (h < 258) { py = 0; px = h; }
  else if (h < 516) { py = 257; px = h - 258; }
  else if (h < 772) { py = h - 516 + 1; px = 0; }
  else { py = h - 772 + 1; px = 257; }
  size_t p = (size_t)b * PP + (size_t)py * PW + px;
  short8 z;
#pragma unroll
  for (int k = 0; k < 8; ++k) z[k] = 0;
#pragma unroll
  for (int c8 = 0; c8 < 8; ++c8) {
    *(short8*)&x[p * 64 + c8 * 8] = z;
    *(short8*)&y[p * 64 + c8 * 8] = z;
  }
  *(short8*)&xp[p * 8] = z;
}

// ---------------------------------------------------------------------------
// pack conv weights [OC, CIN, 3, 3] fp32 -> wp [OCPAD][TPAD*CPAD] bf16
// k = t*CPAD + ic ; zero rows/cols for padding
// ---------------------------------------------------------------------------
__global__ void pack_w_k(const float* __restrict__ w, ushort* __restrict__ wp,
                         int OC, int CIN, int CPAD, int TPAD, int total) {
  int i = blockIdx.x * 256 + threadIdx.x;
  if (i >= total) return;
  int K = TPAD * CPAD;
  int oc = i / K;
  int r = i - oc * K;
  int t = r / CPAD;
  int ic = r - t * CPAD;
  float v = 0.f;
  if (oc < OC && ic < CIN && t < 9) v = w[(oc * CIN + ic) * 9 + t];
  wp[i] = f2bf(v);
}

// ---------------------------------------------------------------------------
// Implicit-GEMM 3x3 conv, bf16 MFMA 16x16x32, padded NHWC in/out.
// Tile: 4 rows x 64 cols (block 256 = 4 waves; wave = 1 output row).
// Wave: 4 mt (64 oc) x 4 nt (64 px). Staging via swizzled global_load_lds.
// K-loop software-pipelined: A depth-2 (global), B depth-1 (LDS).
// ---------------------------------------------------------------------------
template <int C, int KS, bool RELU, bool RESID>
__global__ __launch_bounds__(256, 3) void conv_mfma_k(
    const ushort* __restrict__ in, const ushort* __restrict__ wp,
    const float* __restrict__ bias, const ushort* __restrict__ resid,
    ushort* __restrict__ out) {
  constexpr int CV = C / 8;           // 16B chunks per pixel
  constexpr int SROW = 66 * CV;       // slots per staged row
  constexpr int TOT = 6 * SROW;       // live slots
  constexpr int LSLOT = ((TOT + 63) / 64) * 64;  // padded (DMA overshoot)
  __shared__ __align__(16) ushort xs[LSLOT * 8];

  const int tid = threadIdx.x;
  const int wave = tid >> 6, lane = tid & 63;
  const int quad = lane >> 4, l15 = lane & 15;
  const int x0 = blockIdx.x * 64, y0 = blockIdx.y * 4, b = blockIdx.z;
  const ushort* inb = in + (size_t)b * PP * C;

  // swizzled DMA staging: rows y0..y0+5 (padded coords), cols x0..x0+65
  for (int s0 = wave * 64; s0 < TOT; s0 += 256) {
    int s = s0 + lane;
    int row, col, chunk;
    if (C == 64) {
      row = s / SROW;
      int r = s - row * SROW;
      col = r >> 3;
      chunk = (r & 7) ^ (col & 7);  // inverse swizzle on source
    } else {
      row = s / 66;
      col = s - row * 66;
      chunk = 0;
    }
    const ushort* g =
        inb + ((size_t)(y0 + row) * PW + (x0 + col)) * C + chunk * 8;
    GLD_LDS(g, &xs[(size_t)s0 * 8]);
  }
  __syncthreads();

  f32x4 acc[4][4];
#pragma unroll
  for (int mt = 0; mt < 4; ++mt)
#pragma unroll
    for (int nt = 0; nt < 4; ++nt)
#pragma unroll
      for (int r = 0; r < 4; ++r) acc[mt][nt][r] = 0.f;

  auto loadA = [&](short8* A, int ks) {
#pragma unroll
    for (int mt = 0; mt < 4; ++mt)
      A[mt] = *(const short8*)&wp[(size_t)(mt * 16 + l15) * (KS * 32) +
                                  ks * 32 + quad * 8];
  };
  auto loadB = [&](short8* B, int ks) {
    int t, chunk;
    if (C == 64) {
      t = ks >> 1;
      chunk = ((ks & 1) << 2) + quad;
    } else {
      t = ks * 4 + quad;
      if (t > 8) t = 8;  // dummy taps: A rows are zero
      chunk = 0;
    }
    int dy = t / 3, dx = t - (t / 3) * 3;
#pragma unroll
    for (int nt = 0; nt < 4; ++nt) {
      int c = nt * 16 + l15 + dx;
      int slot = (C == 64) ? ((wave + dy) * SROW + c * 8 + (chunk ^ (c & 7)))
                           : ((wave + dy) * 66 + c);
      B[nt] = *(const short8*)&xs[(size_t)slot * 8];
    }
  };

  short8 A0[4], A1[4], A2[4], B0[4], B1[4];
  loadA(A0, 0);
  if (KS > 1) loadA(A1, 1);
  loadB(B0, 0);
#pragma unroll
  for (int ks = 0; ks < KS; ++ks) {
    if (ks + 2 < KS) loadA(A2, ks + 2);
    if (ks + 1 < KS) loadB(B1, ks + 1);
#pragma unroll
    for (int nt = 0; nt < 4; ++nt)
#pragma unroll
      for (int mt = 0; mt < 4; ++mt)
        acc[mt][nt] = __builtin_amdgcn_mfma_f32_16x16x32_bf16(
            A0[mt], B0[nt], acc[mt][nt], 0, 0, 0);
#pragma unroll
    for (int mt = 0; mt < 4; ++mt) { A0[mt] = A1[mt]; A1[mt] = A2[mt]; }
#pragma unroll
    for (int nt = 0; nt < 4; ++nt) B0[nt] = B1[nt];
  }

  // epilogue: C/D layout col=l15 (pixel), row=quad*4+reg (oc)
  const int yw = y0 + wave;
#pragma unroll
  for (int mt = 0; mt < 4; ++mt) {
    const float4 bb = *(const float4*)&bias[mt * 16 + quad * 4];
#pragma unroll
    for (int nt = 0; nt < 4; ++nt) {
      int px = x0 + nt * 16 + l15;
      size_t base = ((size_t)b * PP + (size_t)(yw + 1) * PW + (px + 1)) * 64 +
                    mt * 16 + quad * 4;
      float v0 = acc[mt][nt][0] + bb.x;
      float v1 = acc[mt][nt][1] + bb.y;
      float v2 = acc[mt][nt][2] + bb.z;
      float v3 = acc[mt][nt][3] + bb.w;
      if (RELU) {
        v0 = fmaxf(v0, 0.f); v1 = fmaxf(v1, 0.f);
        v2 = fmaxf(v2, 0.f); v3 = fmaxf(v3, 0.f);
      }
      if (RESID) {
        short4v rv = *(const short4v*)&resid[base];
        v0 += bf2f((ushort)rv[0]); v1 += bf2f((ushort)rv[1]);
        v2 += bf2f((ushort)rv[2]); v3 += bf2f((ushort)rv[3]);
      }
      short4v o;
      o[0] = (short)f2bf(v0); o[1] = (short)f2bf(v1);
      o[2] = (short)f2bf(v2); o[3] = (short)f2bf(v3);
      *(short4v*)&out[base] = o;
    }
  }
}

// ---------------------------------------------------------------------------
// Fused out-conv (64->225 pad 256) + abs-softmax + 15x15 kernel-conv.
// Block 256 = 4 waves, 64-px row tile; wave w computes oc [w*64, w*64+64).
// Pipelined K-loop; |core+bias| exchanged via fp16 LDS (stride 264, aliases
// the x tile); vectorized consumer with magic div-by-15.
// ---------------------------------------------------------------------------
__global__ __launch_bounds__(256, 3) void out_kc_k(
    const ushort* __restrict__ x, const ushort* __restrict__ wpo,
    const float* __restrict__ b_out, const float* __restrict__ data,
    float* __restrict__ pred) {
  __shared__ __align__(16) char regA[64 * 264 * 2];  // xs 25600B | core 33792B
  __shared__ float dsh[3][15][78];
  __shared__ float bsh[256];
  ushort* xs = (ushort*)regA;
  _Float16* coreSh = (_Float16*)regA;

  const int tid = threadIdx.x;
  const int wave = tid >> 6, lane = tid & 63;
  const int quad = lane >> 4, l15 = lane & 15;
  const int x0 = blockIdx.x * 64, y = blockIdx.y, b = blockIdx.z;

  // swizzled DMA staging of x: 3 padded rows y..y+2, cols x0..x0+65
  for (int s0 = wave * 64; s0 < 3 * 528; s0 += 256) {
    int s = s0 + lane;
    int row = s / 528;
    int r = s - row * 528;
    int col = r >> 3;
    int chunk = (r & 7) ^ (col & 7);
    const ushort* g = x + ((size_t)b * PP + (size_t)(y + row) * PW +
                           (x0 + col)) * 64 + chunk * 8;
    GLD_LDS(g, &xs[(size_t)s0 * 8]);
  }
  bsh[tid] = (tid < 225) ? b_out[tid] : 0.f;
  // stage data halo [3][15][78] fp32 (pad 7, zero-fill; data is unpadded)
  for (int i = tid; i < 3 * 15 * 78; i += 256) {
    int ch = i / 1170;
    int rem = i - ch * 1170;
    int r = rem / 78;
    int cc = rem - r * 78;
    int gy = y - 7 + r, gx = x0 - 7 + cc;
    float v = 0.f;
    if ((unsigned)gy < (unsigned)HW && (unsigned)gx < (unsigned)HW)
      v = data[((b * 3 + ch) << 16) + (gy << 8) + gx];
    dsh[ch][r][cc] = v;
  }
  __syncthreads();

  f32x4 acc[4][4];
#pragma unroll
  for (int mt = 0; mt < 4; ++mt)
#pragma unroll
    for (int nt = 0; nt < 4; ++nt)
#pragma unroll
      for (int r = 0; r < 4; ++r) acc[mt][nt][r] = 0.f;

  auto loadA = [&](short8* A, int ks) {
#pragma unroll
    for (int mt = 0; mt < 4; ++mt)
      A[mt] = *(const short8*)&wpo[(size_t)(wave * 64 + mt * 16 + l15) * 576 +
                                   ks * 32 + quad * 8];
  };
  auto loadB = [&](short8* B, int ks) {
    int t = ks >> 1;
    int dy = t / 3, dx = t - (t / 3) * 3;
    int chunk = ((ks & 1) << 2) + quad;
#pragma unroll
    for (int nt = 0; nt < 4; ++nt) {
      int c = nt * 16 + l15 + dx;
      int slot = dy * 528 + c * 8 + (chunk ^ (c & 7));
      B[nt] = *(const short8*)&xs[(size_t)slot * 8];
    }
  };

  short8 A0[4], A1[4], A2[4], B0[4], B1[4];
  loadA(A0, 0);
  loadA(A1, 1);
  loadB(B0, 0);
#pragma unroll
  for (int ks = 0; ks < 18; ++ks) {
    if (ks + 2 < 18) loadA(A2, ks + 2);
    if (ks + 1 < 18) loadB(B1, ks + 1);
#pragma unroll
    for (int nt = 0; nt < 4; ++nt)
#pragma unroll
      for (int mt = 0; mt < 4; ++mt)
        acc[mt][nt] = __builtin_amdgcn_mfma_f32_16x16x32_bf16(
            A0[mt], B0[nt], acc[mt][nt], 0, 0, 0);
#pragma unroll
    for (int mt = 0; mt < 4; ++mt) { A0[mt] = A1[mt]; A1[mt] = A2[mt]; }
#pragma unroll
    for (int nt = 0; nt < 4; ++nt) B0[nt] = B1[nt];
  }
  __syncthreads();  // retire xs reads before aliasing as coreSh

  // producer: |core + bias| (masked -> -1e4) as fp16, row stride 264
#pragma unroll
  for (int mt = 0; mt < 4; ++mt) {
    int c0 = wave * 64 + mt * 16 + quad * 4;
#pragma unroll
    for (int nt = 0; nt < 4; ++nt) {
      int px = nt * 16 + l15;
      h4 hv;
#pragma unroll
      for (int r = 0; r < 4; ++r) {
        int c = c0 + r;
        float a = acc[mt][nt][r] + bsh[c];
        a = (c < 225) ? fabsf(a) : -1e4f;
        hv[r] = (_Float16)a;
      }
      *(h4*)&coreSh[px * 264 + c0] = hv;
    }
  }
  __syncthreads();

  // consumer: lane -> (px = wave*16+l15, channel quarter = quad)
  const int px = wave * 16 + l15;
  const int cbase = quad * 64;
  h8 vals[8];
#pragma unroll
  for (int v = 0; v < 8; ++v)
    vals[v] = *(h8*)&coreSh[px * 264 + cbase + v * 8];

  float m = 0.f;  // |core| >= 0, masked entries are negative
#pragma unroll
  for (int v = 0; v < 8; ++v)
#pragma unroll
    for (int z = 0; z < 8; ++z) m = fmaxf(m, (float)vals[v][z]);
  m = fmaxf(m, __shfl_xor(m, 16));
  m = fmaxf(m, __shfl_xor(m, 32));

  float l = 0.f, p0 = 0.f, p1 = 0.f, p2 = 0.f;
#pragma unroll
  for (int v = 0; v < 8; ++v)
#pragma unroll
    for (int z = 0; z < 8; ++z) {
      int c = cbase + v * 8 + z;
      float a = (float)vals[v][z];
      float e = __expf(a - m);  // masked channels underflow to 0
      l += e;
      if (c < 225) {
        int di = (int)(((unsigned)c * 34953u) >> 19);  // c/15 exact for c<3850
        int dj = c - di * 15;
        p0 += e * dsh[0][di][px + dj];
        p1 += e * dsh[1][di][px + dj];
        p2 += e * dsh[2][di][px + dj];
      }
    }
  l += __shfl_xor(l, 16);  l += __shfl_xor(l, 32);
  p0 += __shfl_xor(p0, 16); p0 += __shfl_xor(p0, 32);
  p1 += __shfl_xor(p1, 16); p1 += __shfl_xor(p1, 32);
  p2 += __shfl_xor(p2, 16); p2 += __shfl_xor(p2, 32);

  if (quad == 0) {
    float inv = 1.f / l;
    int pix = (y << 8) + x0 + px;
    pred[((b * 3 + 0) << 16) + pix] = p0 * inv;
    pred[((b * 3 + 1) << 16) + pix] = p1 * inv;
    pred[((b * 3 + 2) << 16) + pix] = p2 * inv;
  }
}

// ---------------------------------------------------------------------------
// data -> d_out[0 : 786432] verbatim copy (float4)
// ---------------------------------------------------------------------------
__global__ void copy_k(const float4* __restrict__ src, float4* __restrict__ dst,
                       int n4) {
  int i = blockIdx.x * blockDim.x + threadIdx.x;
  if (i < n4) dst[i] = src[i];
}

extern "C" void kernel_launch(void* const* d_in, const int* in_sizes, int n_in,
                              void* d_out, int out_size, void* d_ws,
                              size_t ws_size, hipStream_t stream) {
  const float* data_with_est = (const float*)d_in[0];
  const float* data = (const float*)d_in[1];
  const float* w_first = (const float*)d_in[2];
  const float* b_first = (const float*)d_in[3];
  const float* wa[3] = {(const float*)d_in[4], (const float*)d_in[8],
                        (const float*)d_in[12]};
  const float* ba[3] = {(const float*)d_in[5], (const float*)d_in[9],
                        (const float*)d_in[13]};
  const float* wb[3] = {(const float*)d_in[6], (const float*)d_in[10],
                        (const float*)d_in[14]};
  const float* bb[3] = {(const float*)d_in[7], (const float*)d_in[11],
                        (const float*)d_in[15]};
  const float* w_out = (const float*)d_in[16];
  const float* b_out = (const float*)d_in[17];

  float* out = (float*)d_out;
  float* pred = out + 4 * 3 * NPIX;

  // workspace layout (ushort units) — order matters: DMA overshoot of each
  // buffer must land in the next mapped region.
  ushort* x = (ushort*)d_ws;               // 4*PP*64
  ushort* y = x + (size_t)4 * PP * 64;     // 4*PP*64
  ushort* xp = y + (size_t)4 * PP * 64;    // 4*PP*8
  ushort* Wp1 = xp + (size_t)4 * PP * 8;   // 64*96
  ushort* Wpr = Wp1 + 64 * 96;             // 6*36864
  ushort* Wpo = Wpr + 6 * 36864;           // 256*576

  // packs + halo zeroing (disjoint writes, any order)
  pack_in_k<<<1024, 256, 0, stream>>>(data_with_est, xp);
  zero_halo_k<<<17, 256, 0, stream>>>(x, y, xp);
  pack_w_k<<<24, 256, 0, stream>>>(w_first, Wp1, 64, 6, 8, 12, 64 * 96);
  for (int i = 0; i < 3; ++i) {
    pack_w_k<<<144, 256, 0, stream>>>(wa[i], Wpr + (2 * i) * 36864, 64, 64, 64,
                                      9, 36864);
    pack_w_k<<<144, 256, 0, stream>>>(wb[i], Wpr + (2 * i + 1) * 36864, 64, 64,
                                      64, 9, 36864);
  }
  pack_w_k<<<576, 256, 0, stream>>>(w_out, Wpo, 225, 64, 64, 9, 256 * 576);

  dim3 cgrid(4, 64, 4), cblk(256);
  // first conv 6->64 (C padded to 8, K padded to 96)
  conv_mfma_k<8, 3, false, false>
      <<<cgrid, cblk, 0, stream>>>(xp, Wp1, b_first, nullptr, x);
  // 3 residual blocks
  for (int i = 0; i < 3; ++i) {
    conv_mfma_k<64, 18, true, false><<<cgrid, cblk, 0, stream>>>(
        x, Wpr + (2 * i) * 36864, ba[i], nullptr, y);
    conv_mfma_k<64, 18, false, true><<<cgrid, cblk, 0, stream>>>(
        y, Wpr + (2 * i + 1) * 36864, bb[i], x, x);
  }
  // fused out-conv + softmax + kernel-conv
  out_kc_k<<<dim3(4, HW, 4), 256, 0, stream>>>(x, Wpo, b_out, data, pred);
  // data passthrough
  int n4 = 4 * 3 * NPIX / 4;
  copy_k<<<(n4 + 255) / 256, 256, 0, stream>>>((const float4*)data,
                                               (float4*)out, n4);
}

// Round 4
// 661.292 us; speedup vs baseline: 12.1599x; 1.1351x over previous
//
#include <hip/hip_runtime.h>

#define HW 256
#define PW 258              // padded width/height
#define PP (PW * PW)        // padded pixels per image
#define NPIX (HW * HW)

using short8 = __attribute__((ext_vector_type(8))) short;
using short4v = __attribute__((ext_vector_type(4))) short;
using f32x4 = __attribute__((ext_vector_type(4))) float;
using h4 = __attribute__((ext_vector_type(4))) _Float16;
using h8 = __attribute__((ext_vector_type(8))) _Float16;

// async global->LDS, 16B per lane; LDS dest = wave-uniform base + lane*16
#define GLD_LDS(g, l)                                                  \
  __builtin_amdgcn_global_load_lds(                                    \
      (const __attribute__((address_space(1))) void*)(g),              \
      (__attribute__((address_space(3))) void*)(l), 16, 0, 0)

static __device__ __forceinline__ ushort f2bf(float f) {
  unsigned u = __float_as_uint(f);
  unsigned r = (u + 0x7FFFu + ((u >> 16) & 1u)) >> 16;  // RNE
  return (ushort)r;
}
static __device__ __forceinline__ float bf2f(ushort u) {
  return __uint_as_float(((unsigned)u) << 16);
}

// ---------------------------------------------------------------------------
// pack data_with_est [4,6,256,256] fp32 NCHW -> xp padded [4][258][258][8] bf16
// ---------------------------------------------------------------------------
__global__ void pack_in_k(const float* __restrict__ din, ushort* __restrict__ xp) {
  int i = blockIdx.x * 256 + threadIdx.x;  // 0 .. 262143
  int b = i >> 16;
  int px = i & 65535;
  int y = px >> 8, x = px & 255;
  short8 v;
#pragma unroll
  for (int z = 0; z < 8; ++z) v[z] = 0;
#pragma unroll
  for (int ic = 0; ic < 6; ++ic)
    v[ic] = (short)f2bf(din[(b * 6 + ic) * NPIX + px]);
  *(short8*)&xp[((size_t)b * PP + (size_t)(y + 1) * PW + (x + 1)) * 8] = v;
}

// ---------------------------------------------------------------------------
// zero the 1-px halo ring of x, y (64ch) and xp (8ch) padded buffers
// ---------------------------------------------------------------------------
__global__ void zero_halo_k(ushort* __restrict__ x, ushort* __restrict__ y,
                            ushort* __restrict__ xp) {
  int i = blockIdx.x * 256 + threadIdx.x;
  if (i >= 4 * 1028) return;
  int b = i / 1028;
  int h = i - b * 1028;
  int py, px;
  if (h < 258) { py = 0; px = h; }
  else if (h < 516) { py = 257; px = h - 258; }
  else if (h < 772) { py = h - 516 + 1; px = 0; }
  else { py = h - 772 + 1; px = 257; }
  size_t p = (size_t)b * PP + (size_t)py * PW + px;
  short8 z;
#pragma unroll
  for (int k = 0; k < 8; ++k) z[k] = 0;
#pragma unroll
  for (int c8 = 0; c8 < 8; ++c8) {
    *(short8*)&x[p * 64 + c8 * 8] = z;
    *(short8*)&y[p * 64 + c8 * 8] = z;
  }
  *(short8*)&xp[p * 8] = z;
}

// ---------------------------------------------------------------------------
// pack conv weights [OC, CIN, 3, 3] fp32 -> wp [OCPAD][TPAD*CPAD] bf16
// ---------------------------------------------------------------------------
__global__ void pack_w_k(const float* __restrict__ w, ushort* __restrict__ wp,
                         int OC, int CIN, int CPAD, int TPAD, int total) {
  int i = blockIdx.x * 256 + threadIdx.x;
  if (i >= total) return;
  int K = TPAD * CPAD;
  int oc = i / K;
  int r = i - oc * K;
  int t = r / CPAD;
  int ic = r - t * CPAD;
  float v = 0.f;
  if (oc < OC && ic < CIN && t < 9) v = w[(oc * CIN + ic) * 9 + t];
  wp[i] = f2bf(v);
}

// ---------------------------------------------------------------------------
// Implicit-GEMM 3x3 conv, bf16 MFMA 16x16x32, padded NHWC.
// MT=2: block = 2 rows x 64 px, 4 waves = (row, ocHalf); wave = 32 oc x 64 px.
// MT=4: block = 4 rows x 64 px, 4 waves = rows; wave = 64 oc x 64 px.
// ALL weight A-fragments register-resident: preload 9 K-steps, rolling reload
// (slot k consumed at ks -> refilled with ks+9; 9-iter prefetch distance).
// K-loop has no latency-critical global loads; LDS B-reads depth-1 prefetched.
// ---------------------------------------------------------------------------
template <int C, int KS, int MT, bool RELU, bool RESID>
__global__ __launch_bounds__(256, MT == 2 ? 3 : 2) void conv_mfma_k(
    const ushort* __restrict__ in, const ushort* __restrict__ wp,
    const float* __restrict__ bias, const ushort* __restrict__ resid,
    ushort* __restrict__ out) {
  constexpr int CV = C / 8;                 // 16B chunks per pixel
  constexpr int SROW = 66 * CV;             // slots per staged row
  constexpr int ROWS = (MT == 2) ? 2 : 4;   // output rows per block
  constexpr int TOT = (ROWS + 2) * SROW;    // live slots
  constexpr int LSLOT = ((TOT + 63) / 64) * 64;
  constexpr int AB = (KS > 9) ? 9 : KS;     // A register buffer depth
  __shared__ __align__(16) ushort xs[LSLOT * 8];

  const int tid = threadIdx.x;
  const int wave = tid >> 6, lane = tid & 63;
  const int quad = lane >> 4, l15 = lane & 15;
  const int rowIdx = (MT == 2) ? (wave & 1) : wave;
  const int ocBase = (MT == 2) ? (wave >> 1) * 32 : 0;
  const int x0 = blockIdx.x * 64, y0 = blockIdx.y * ROWS, b = blockIdx.z;
  const ushort* inb = in + (size_t)b * PP * C;

  // swizzled DMA staging: padded rows y0..y0+ROWS+1, cols x0..x0+65
  for (int s0 = wave * 64; s0 < TOT; s0 += 256) {
    int s = s0 + lane;
    int row, col, chunk;
    if (C == 64) {
      row = s / SROW;
      int r = s - row * SROW;
      col = r >> 3;
      chunk = (r & 7) ^ (col & 7);  // inverse swizzle on source
    } else {
      row = s / 66;
      col = s - row * 66;
      chunk = 0;
    }
    const ushort* g =
        inb + ((size_t)(y0 + row) * PW + (x0 + col)) * C + chunk * 8;
    GLD_LDS(g, &xs[(size_t)s0 * 8]);
  }

  // ---- register-resident weights ----
  short8 Wa[MT][AB];
  auto loadA = [&](int slot, int ks) {
#pragma unroll
    for (int mt = 0; mt < MT; ++mt)
      Wa[mt][slot] = *(const short8*)&wp[(size_t)(ocBase + mt * 16 + l15) *
                                             (KS * 32) + ks * 32 + quad * 8];
  };
#pragma unroll
  for (int ks = 0; ks < AB; ++ks) loadA(ks, ks);

  __syncthreads();

  f32x4 acc[MT][4];
#pragma unroll
  for (int mt = 0; mt < MT; ++mt)
#pragma unroll
    for (int nt = 0; nt < 4; ++nt)
#pragma unroll
      for (int r = 0; r < 4; ++r) acc[mt][nt][r] = 0.f;

  auto loadB = [&](short8* B, int ks) {
    int t, chunk;
    if (C == 64) {
      t = ks >> 1;
      chunk = ((ks & 1) << 2) + quad;
    } else {
      t = ks * 4 + quad;
      if (t > 8) t = 8;  // dummy taps: A rows are zero
      chunk = 0;
    }
    int dy = t / 3, dx = t - (t / 3) * 3;
#pragma unroll
    for (int nt = 0; nt < 4; ++nt) {
      int c = nt * 16 + l15 + dx;
      int slot = (C == 64)
                     ? ((rowIdx + dy) * SROW + c * 8 + (chunk ^ (c & 7)))
                     : ((rowIdx + dy) * 66 + c);
      B[nt] = *(const short8*)&xs[(size_t)slot * 8];
    }
  };

  short8 B0[4], B1[4];
  loadB(B0, 0);
#pragma unroll
  for (int ks = 0; ks < KS; ++ks) {
    if (ks + 1 < KS) loadB(B1, ks + 1);
    const int slot = ks % AB;
#pragma unroll
    for (int nt = 0; nt < 4; ++nt)
#pragma unroll
      for (int mt = 0; mt < MT; ++mt)
        acc[mt][nt] = __builtin_amdgcn_mfma_f32_16x16x32_bf16(
            Wa[mt][slot], B0[nt], acc[mt][nt], 0, 0, 0);
    if (AB < KS && ks + AB < KS) loadA(slot, ks + AB);  // rolling refill (WAR)
#pragma unroll
    for (int nt = 0; nt < 4; ++nt) B0[nt] = B1[nt];
  }

  // epilogue: C/D layout col=l15 (pixel), row=quad*4+reg (oc)
  const int yw = y0 + rowIdx;
#pragma unroll
  for (int mt = 0; mt < MT; ++mt) {
    const float4 bb = *(const float4*)&bias[ocBase + mt * 16 + quad * 4];
#pragma unroll
    for (int nt = 0; nt < 4; ++nt) {
      int px = x0 + nt * 16 + l15;
      size_t base = ((size_t)b * PP + (size_t)(yw + 1) * PW + (px + 1)) * 64 +
                    ocBase + mt * 16 + quad * 4;
      float v0 = acc[mt][nt][0] + bb.x;
      float v1 = acc[mt][nt][1] + bb.y;
      float v2 = acc[mt][nt][2] + bb.z;
      float v3 = acc[mt][nt][3] + bb.w;
      if (RELU) {
        v0 = fmaxf(v0, 0.f); v1 = fmaxf(v1, 0.f);
        v2 = fmaxf(v2, 0.f); v3 = fmaxf(v3, 0.f);
      }
      if (RESID) {
        short4v rv = *(const short4v*)&resid[base];
        v0 += bf2f((ushort)rv[0]); v1 += bf2f((ushort)rv[1]);
        v2 += bf2f((ushort)rv[2]); v3 += bf2f((ushort)rv[3]);
      }
      short4v o;
      o[0] = (short)f2bf(v0); o[1] = (short)f2bf(v1);
      o[2] = (short)f2bf(v2); o[3] = (short)f2bf(v3);
      *(short4v*)&out[base] = o;
    }
  }
}

// ---------------------------------------------------------------------------
// Fused out-conv (64->225 pad 256) + abs-softmax + 15x15 kernel-conv.
// Block 512 = 8 waves; wave w computes oc [w*32, w*32+32) for a 64-px row.
// Register-resident rolling-A weights as in conv. Consumer: lane ->
// (px = (w&3)*16+l15, cgroup = (w>>2)*4+quad, 32 ch); quad-shfl + LDS
// cross-half reduction.
// ---------------------------------------------------------------------------
__global__ __launch_bounds__(512, 2) void out_kc_k(
    const ushort* __restrict__ x, const ushort* __restrict__ wpo,
    const float* __restrict__ b_out, const float* __restrict__ data,
    float* __restrict__ pred) {
  __shared__ __align__(16) char regA[64 * 264 * 2];  // xs 25.6KB | core 33.8KB
  __shared__ float dsh[3][15][78];
  __shared__ float bsh[256];
  __shared__ float partM[2][64], partL[2][64], partP[3][2][64];
  ushort* xs = (ushort*)regA;
  _Float16* coreSh = (_Float16*)regA;  // [64 px][264]

  const int tid = threadIdx.x;
  const int wave = tid >> 6, lane = tid & 63;
  const int quad = lane >> 4, l15 = lane & 15;
  const int ocBase = wave * 32;
  const int x0 = blockIdx.x * 64, y = blockIdx.y, b = blockIdx.z;

  // swizzled DMA staging of x: 3 padded rows y..y+2, cols x0..x0+65
  for (int s0 = wave * 64; s0 < 3 * 528; s0 += 512) {
    int s = s0 + lane;
    int row = s / 528;
    int r = s - row * 528;
    int col = r >> 3;
    int chunk = (r & 7) ^ (col & 7);
    const ushort* g = x + ((size_t)b * PP + (size_t)(y + row) * PW +
                           (x0 + col)) * 64 + chunk * 8;
    GLD_LDS(g, &xs[(size_t)s0 * 8]);
  }
  if (tid < 256) bsh[tid] = (tid < 225) ? b_out[tid] : 0.f;
  // stage data halo [3][15][78] fp32 (pad 7, zero-fill; data unpadded)
  for (int i = tid; i < 3 * 15 * 78; i += 512) {
    int ch = i / 1170;
    int rem = i - ch * 1170;
    int r = rem / 78;
    int cc = rem - r * 78;
    int gy = y - 7 + r, gx = x0 - 7 + cc;
    float v = 0.f;
    if ((unsigned)gy < (unsigned)HW && (unsigned)gx < (unsigned)HW)
      v = data[((b * 3 + ch) << 16) + (gy << 8) + gx];
    dsh[ch][r][cc] = v;
  }

  // register-resident rolling-A weights (32 oc per wave)
  short8 Wa[2][9];
  auto loadA = [&](int slot, int ks) {
#pragma unroll
    for (int mt = 0; mt < 2; ++mt)
      Wa[mt][slot] = *(const short8*)&wpo[(size_t)(ocBase + mt * 16 + l15) *
                                              576 + ks * 32 + quad * 8];
  };
#pragma unroll
  for (int ks = 0; ks < 9; ++ks) loadA(ks, ks);

  __syncthreads();

  f32x4 acc[2][4];
#pragma unroll
  for (int mt = 0; mt < 2; ++mt)
#pragma unroll
    for (int nt = 0; nt < 4; ++nt)
#pragma unroll
      for (int r = 0; r < 4; ++r) acc[mt][nt][r] = 0.f;

  auto loadB = [&](short8* B, int ks) {
    int t = ks >> 1;
    int dy = t / 3, dx = t - (t / 3) * 3;
    int chunk = ((ks & 1) << 2) + quad;
#pragma unroll
    for (int nt = 0; nt < 4; ++nt) {
      int c = nt * 16 + l15 + dx;
      int slot = dy * 528 + c * 8 + (chunk ^ (c & 7));
      B[nt] = *(const short8*)&xs[(size_t)slot * 8];
    }
  };

  short8 B0[4], B1[4];
  loadB(B0, 0);
#pragma unroll
  for (int ks = 0; ks < 18; ++ks) {
    if (ks + 1 < 18) loadB(B1, ks + 1);
    const int slot = ks % 9;
#pragma unroll
    for (int nt = 0; nt < 4; ++nt)
#pragma unroll
      for (int mt = 0; mt < 2; ++mt)
        acc[mt][nt] = __builtin_amdgcn_mfma_f32_16x16x32_bf16(
            Wa[mt][slot], B0[nt], acc[mt][nt], 0, 0, 0);
    if (ks + 9 < 18) loadA(slot, ks + 9);  // rolling refill
#pragma unroll
    for (int nt = 0; nt < 4; ++nt) B0[nt] = B1[nt];
  }
  __syncthreads();  // retire xs reads before aliasing as coreSh

  // producer: |core + bias| (masked -> -1e4) as fp16, row stride 264
#pragma unroll
  for (int mt = 0; mt < 2; ++mt) {
    int c0 = ocBase + mt * 16 + quad * 4;
#pragma unroll
    for (int nt = 0; nt < 4; ++nt) {
      int px = nt * 16 + l15;
      h4 hv;
#pragma unroll
      for (int r = 0; r < 4; ++r) {
        int c = c0 + r;
        float a = acc[mt][nt][r] + bsh[c];
        a = (c < 225) ? fabsf(a) : -1e4f;
        hv[r] = (_Float16)a;
      }
      *(h4*)&coreSh[px * 264 + c0] = hv;
    }
  }
  __syncthreads();

  // consumer: lane -> (px = (w&3)*16+l15, cgroup = (w>>2)*4+quad)
  const int px = (wave & 3) * 16 + l15;
  const int half = wave >> 2;
  const int cbase = ((half * 4) + quad) * 32;
  h8 vals[4];
#pragma unroll
  for (int v = 0; v < 4; ++v)
    vals[v] = *(h8*)&coreSh[px * 264 + cbase + v * 8];

  float m = 0.f;  // |core| >= 0; masked entries negative
#pragma unroll
  for (int v = 0; v < 4; ++v)
#pragma unroll
    for (int z = 0; z < 8; ++z) m = fmaxf(m, (float)vals[v][z]);
  m = fmaxf(m, __shfl_xor(m, 16));
  m = fmaxf(m, __shfl_xor(m, 32));
  if (quad == 0) partM[half][px] = m;
  __syncthreads();
  m = fmaxf(partM[0][px], partM[1][px]);

  float l = 0.f, p0 = 0.f, p1 = 0.f, p2 = 0.f;
#pragma unroll
  for (int v = 0; v < 4; ++v)
#pragma unroll
    for (int z = 0; z < 8; ++z) {
      int c = cbase + v * 8 + z;
      float a = (float)vals[v][z];
      float e = __expf(a - m);  // masked channels underflow to 0
      l += e;
      if (c < 225) {
        int di = (int)(((unsigned)c * 34953u) >> 19);  // c/15 exact
        int dj = c - di * 15;
        p0 += e * dsh[0][di][px + dj];
        p1 += e * dsh[1][di][px + dj];
        p2 += e * dsh[2][di][px + dj];
      }
    }
  l += __shfl_xor(l, 16);  l += __shfl_xor(l, 32);
  p0 += __shfl_xor(p0, 16); p0 += __shfl_xor(p0, 32);
  p1 += __shfl_xor(p1, 16); p1 += __shfl_xor(p1, 32);
  p2 += __shfl_xor(p2, 16); p2 += __shfl_xor(p2, 32);
  if (quad == 0) {
    partL[half][px] = l;
    partP[0][half][px] = p0;
    partP[1][half][px] = p1;
    partP[2][half][px] = p2;
  }
  __syncthreads();

  if (tid < 64) {
    int p = tid;
    float linv = 1.f / (partL[0][p] + partL[1][p]);
    int pix = (y << 8) + x0 + p;
#pragma unroll
    for (int ch = 0; ch < 3; ++ch)
      pred[((b * 3 + ch) << 16) + pix] =
          (partP[ch][0][p] + partP[ch][1][p]) * linv;
  }
}

// ---------------------------------------------------------------------------
// data -> d_out[0 : 786432] verbatim copy (float4)
// ---------------------------------------------------------------------------
__global__ void copy_k(const float4* __restrict__ src, float4* __restrict__ dst,
                       int n4) {
  int i = blockIdx.x * blockDim.x + threadIdx.x;
  if (i < n4) dst[i] = src[i];
}

extern "C" void kernel_launch(void* const* d_in, const int* in_sizes, int n_in,
                              void* d_out, int out_size, void* d_ws,
                              size_t ws_size, hipStream_t stream) {
  const float* data_with_est = (const float*)d_in[0];
  const float* data = (const float*)d_in[1];
  const float* w_first = (const float*)d_in[2];
  const float* b_first = (const float*)d_in[3];
  const float* wa[3] = {(const float*)d_in[4], (const float*)d_in[8],
                        (const float*)d_in[12]};
  const float* ba[3] = {(const float*)d_in[5], (const float*)d_in[9],
                        (const float*)d_in[13]};
  const float* wb[3] = {(const float*)d_in[6], (const float*)d_in[10],
                        (const float*)d_in[14]};
  const float* bb[3] = {(const float*)d_in[7], (const float*)d_in[11],
                        (const float*)d_in[15]};
  const float* w_out = (const float*)d_in[16];
  const float* b_out = (const float*)d_in[17];

  float* out = (float*)d_out;
  float* pred = out + 4 * 3 * NPIX;

  // workspace layout (ushort units) — DMA overshoot of each buffer must land
  // in the next mapped region.
  ushort* x = (ushort*)d_ws;               // 4*PP*64
  ushort* y = x + (size_t)4 * PP * 64;     // 4*PP*64
  ushort* xp = y + (size_t)4 * PP * 64;    // 4*PP*8
  ushort* Wp1 = xp + (size_t)4 * PP * 8;   // 64*96
  ushort* Wpr = Wp1 + 64 * 96;             // 6*36864
  ushort* Wpo = Wpr + 6 * 36864;           // 256*576

  // packs + halo zeroing
  pack_in_k<<<1024, 256, 0, stream>>>(data_with_est, xp);
  zero_halo_k<<<17, 256, 0, stream>>>(x, y, xp);
  pack_w_k<<<24, 256, 0, stream>>>(w_first, Wp1, 64, 6, 8, 12, 64 * 96);
  for (int i = 0; i < 3; ++i) {
    pack_w_k<<<144, 256, 0, stream>>>(wa[i], Wpr + (2 * i) * 36864, 64, 64, 64,
                                      9, 36864);
    pack_w_k<<<144, 256, 0, stream>>>(wb[i], Wpr + (2 * i + 1) * 36864, 64, 64,
                                      64, 9, 36864);
  }
  pack_w_k<<<576, 256, 0, stream>>>(w_out, Wpo, 225, 64, 64, 9, 256 * 576);

  // first conv 6->64 (C padded to 8, K padded to 96): MT=4, 4 rows/block
  conv_mfma_k<8, 3, 4, false, false><<<dim3(4, 64, 4), 256, 0, stream>>>(
      xp, Wp1, b_first, nullptr, x);
  // 3 residual blocks: MT=2, 2 rows/block
  dim3 cgrid(4, 128, 4);
  for (int i = 0; i < 3; ++i) {
    conv_mfma_k<64, 18, 2, true, false><<<cgrid, 256, 0, stream>>>(
        x, Wpr + (2 * i) * 36864, ba[i], nullptr, y);
    conv_mfma_k<64, 18, 2, false, true><<<cgrid, 256, 0, stream>>>(
        y, Wpr + (2 * i + 1) * 36864, bb[i], x, x);
  }
  // fused out-conv + softmax + kernel-conv (512-thread blocks)
  out_kc_k<<<dim3(4, HW, 4), 512, 0, stream>>>(x, Wpo, b_out, data, pred);
  // data passthrough
  int n4 = 4 * 3 * NPIX / 4;
  copy_k<<<(n4 + 255) / 256, 256, 0, stream>>>((const float4*)data,
                                               (float4*)out, n4);
}

// Round 5
// 500.196 us; speedup vs baseline: 16.0761x; 1.3221x over previous
//
#include <hip/hip_runtime.h>

#define HW 256
#define PW 258              // padded width/height
#define PP (PW * PW)        // padded pixels per image
#define NPIX (HW * HW)

using short8 = __attribute__((ext_vector_type(8))) short;
using short4v = __attribute__((ext_vector_type(4))) short;
using f32x4 = __attribute__((ext_vector_type(4))) float;
using h4 = __attribute__((ext_vector_type(4))) _Float16;
using h8 = __attribute__((ext_vector_type(8))) _Float16;

// async global->LDS, 16B per lane; LDS dest = wave-uniform base + lane*16
#define GLD_LDS(g, l)                                                  \
  __builtin_amdgcn_global_load_lds(                                    \
      (const __attribute__((address_space(1))) void*)(g),              \
      (__attribute__((address_space(3))) void*)(l), 16, 0, 0)

static __device__ __forceinline__ ushort f2bf(float f) {
  unsigned u = __float_as_uint(f);
  unsigned r = (u + 0x7FFFu + ((u >> 16) & 1u)) >> 16;  // RNE
  return (ushort)r;
}
static __device__ __forceinline__ float bf2f(ushort u) {
  return __uint_as_float(((unsigned)u) << 16);
}

// ---------------------------------------------------------------------------
// pack data_with_est [4,6,256,256] fp32 NCHW -> xp padded [4][258][258][8] bf16
// ---------------------------------------------------------------------------
__global__ void pack_in_k(const float* __restrict__ din, ushort* __restrict__ xp) {
  int i = blockIdx.x * 256 + threadIdx.x;  // 0 .. 262143
  int b = i >> 16;
  int px = i & 65535;
  int y = px >> 8, x = px & 255;
  short8 v;
#pragma unroll
  for (int z = 0; z < 8; ++z) v[z] = 0;
#pragma unroll
  for (int ic = 0; ic < 6; ++ic)
    v[ic] = (short)f2bf(din[(b * 6 + ic) * NPIX + px]);
  *(short8*)&xp[((size_t)b * PP + (size_t)(y + 1) * PW + (x + 1)) * 8] = v;
}

// ---------------------------------------------------------------------------
// zero the 1-px halo ring of x, y (64ch) and xp (8ch) padded buffers
// ---------------------------------------------------------------------------
__global__ void zero_halo_k(ushort* __restrict__ x, ushort* __restrict__ y,
                            ushort* __restrict__ xp) {
  int i = blockIdx.x * 256 + threadIdx.x;
  if (i >= 4 * 1028) return;
  int b = i / 1028;
  int h = i - b * 1028;
  int py, px;
  if (h < 258) { py = 0; px = h; }
  else if (h < 516) { py = 257; px = h - 258; }
  else if (h < 772) { py = h - 516 + 1; px = 0; }
  else { py = h - 772 + 1; px = 257; }
  size_t p = (size_t)b * PP + (size_t)py * PW + px;
  short8 z;
#pragma unroll
  for (int k = 0; k < 8; ++k) z[k] = 0;
#pragma unroll
  for (int c8 = 0; c8 < 8; ++c8) {
    *(short8*)&x[p * 64 + c8 * 8] = z;
    *(short8*)&y[p * 64 + c8 * 8] = z;
  }
  *(short8*)&xp[p * 8] = z;
}

// ---------------------------------------------------------------------------
// pack conv weights [OC,CIN,3,3] fp32 -> MFMA A-fragment order bf16:
//   wf[((ks*NG + g)*64 + lane)*8 + j]
//   oc = g*16 + (lane&15);  k = ks*32 + (lane>>4)*8 + j;  t = k/CPAD; ic = k%CPAD
// A-frag read in-kernel = one wave-contiguous 1KB ds_read_b128 (conflict-free).
// ---------------------------------------------------------------------------
__global__ void pack_wfrag_k(const float* __restrict__ w,
                             ushort* __restrict__ wf, int OC, int CIN,
                             int CPAD, int NG, int total) {
  int i = blockIdx.x * 256 + threadIdx.x;
  if (i >= total) return;
  int j = i & 7;
  int lane = (i >> 3) & 63;
  int rest = i >> 9;
  int g = rest % NG;
  int ks = rest / NG;
  int oc = g * 16 + (lane & 15);
  int k = ks * 32 + (lane >> 4) * 8 + j;
  int t = k / CPAD;
  int ic = k - t * CPAD;
  float v = 0.f;
  if (oc < OC && t < 9 && ic < CIN) v = w[(oc * CIN + ic) * 9 + t];
  wf[i] = f2bf(v);
}

// ---------------------------------------------------------------------------
// Implicit-GEMM 3x3 conv, bf16 MFMA 16x16x32, padded NHWC, m97-style:
// both operands in LDS. Block 256 = 4 waves = 4 output rows; wave = 64oc x
// 64px (4 mt x 4 nt -> 8 ds_read_b128 : 16 MFMA per ks). Weights double-
// buffered in LDS in 3-ks chunks (12.3KB/buf), DMA'd while computing the
// previous chunk. C=8 first conv: single 12.3KB weight stage, no chunking.
// ---------------------------------------------------------------------------
template <int C, int KS, bool RELU, bool RESID>
__global__ __launch_bounds__(256, 2) void conv_mfma_k(
    const ushort* __restrict__ in, const ushort* __restrict__ wf,
    const float* __restrict__ bias, const ushort* __restrict__ resid,
    ushort* __restrict__ out) {
  constexpr int CV = C / 8;                 // 16B chunks per pixel
  constexpr int SROW = 66 * CV;             // slots per staged row
  constexpr int TOT = 6 * SROW;             // live slots (4 rows + halo)
  constexpr int LSLOT = ((TOT + 63) / 64) * 64;
  constexpr int NCH = KS / 3;               // weight chunks (6 or 1)
  constexpr int NBUF = (NCH > 1) ? 2 : 1;
  constexpr int CHW = 3 * 4 * 64 * 8;       // halfwords per chunk (12.3KB)
  __shared__ __align__(16) ushort wLds[NBUF * CHW];
  __shared__ __align__(16) ushort xs[LSLOT * 8];

  const int tid = threadIdx.x;
  const int wave = tid >> 6, lane = tid & 63;
  const int quad = lane >> 4, l15 = lane & 15;
  const int x0 = blockIdx.x * 64, y0 = blockIdx.y * 4, b = blockIdx.z;
  const ushort* inb = in + (size_t)b * PP * C;

  // stage activation tile: padded rows y0..y0+5, cols x0..x0+65 (swizzled)
  for (int s0 = wave * 64; s0 < TOT; s0 += 256) {
    int s = s0 + lane;
    int row, col, chunk;
    if (C == 64) {
      row = s / SROW;
      int r = s - row * SROW;
      col = r >> 3;
      chunk = (r & 7) ^ (col & 7);  // inverse swizzle on source
    } else {
      row = s / 66;
      col = s - row * 66;
      chunk = 0;
    }
    GLD_LDS(inb + ((size_t)(y0 + row) * PW + (x0 + col)) * C + chunk * 8,
            &xs[(size_t)s0 * 8]);
  }
  // stage weight chunk 0 (identity copy, fragment order)
#pragma unroll
  for (int r = 0; r < 3; ++r) {
    int s0 = r * 256 + wave * 64;
    GLD_LDS(wf + (size_t)(s0 + lane) * 8, &wLds[s0 * 8]);
  }
  __syncthreads();

  f32x4 acc[4][4];
#pragma unroll
  for (int mt = 0; mt < 4; ++mt)
#pragma unroll
    for (int nt = 0; nt < 4; ++nt)
#pragma unroll
      for (int r = 0; r < 4; ++r) acc[mt][nt][r] = 0.f;

#pragma unroll
  for (int ch = 0; ch < NCH; ++ch) {
    if (ch + 1 < NCH) {  // DMA next chunk while computing this one
      const ushort* src = wf + (size_t)(ch + 1) * CHW;
      ushort* dst = &wLds[((ch + 1) % NBUF) * CHW];
#pragma unroll
      for (int r = 0; r < 3; ++r) {
        int s0 = r * 256 + wave * 64;
        GLD_LDS(src + (size_t)(s0 + lane) * 8, dst + s0 * 8);
      }
    }
    const ushort* wb = &wLds[(ch % NBUF) * CHW];
#pragma unroll
    for (int ksl = 0; ksl < 3; ++ksl) {
      const int ks = ch * 3 + ksl;
      short8 A[4], B[4];
#pragma unroll
      for (int mt = 0; mt < 4; ++mt)
        A[mt] = *(const short8*)&wb[((ksl * 4 + mt) * 64 + lane) * 8];
      int t, chunk;
      if (C == 64) {
        t = ks >> 1;
        chunk = ((ks & 1) << 2) + quad;
      } else {
        t = ks * 4 + quad;
        if (t > 8) t = 8;  // dummy taps: A rows are zero
        chunk = 0;
      }
      int dy = t / 3, dx = t - (t / 3) * 3;
#pragma unroll
      for (int nt = 0; nt < 4; ++nt) {
        int c = nt * 16 + l15 + dx;
        int slot = (C == 64)
                       ? ((wave + dy) * SROW + c * 8 + (chunk ^ (c & 7)))
                       : ((wave + dy) * 66 + c);
        B[nt] = *(const short8*)&xs[(size_t)slot * 8];
      }
#pragma unroll
      for (int nt = 0; nt < 4; ++nt)
#pragma unroll
        for (int mt = 0; mt < 4; ++mt)
          acc[mt][nt] = __builtin_amdgcn_mfma_f32_16x16x32_bf16(
              A[mt], B[nt], acc[mt][nt], 0, 0, 0);
    }
    if (NCH > 1) __syncthreads();
  }

  // epilogue: C/D layout col=l15 (pixel), row=quad*4+reg (oc)
  const int yw = y0 + wave;
#pragma unroll
  for (int mt = 0; mt < 4; ++mt) {
    const float4 bb = *(const float4*)&bias[mt * 16 + quad * 4];
#pragma unroll
    for (int nt = 0; nt < 4; ++nt) {
      int px = x0 + nt * 16 + l15;
      size_t base = ((size_t)b * PP + (size_t)(yw + 1) * PW + (px + 1)) * 64 +
                    mt * 16 + quad * 4;
      float v0 = acc[mt][nt][0] + bb.x;
      float v1 = acc[mt][nt][1] + bb.y;
      float v2 = acc[mt][nt][2] + bb.z;
      float v3 = acc[mt][nt][3] + bb.w;
      if (RELU) {
        v0 = fmaxf(v0, 0.f); v1 = fmaxf(v1, 0.f);
        v2 = fmaxf(v2, 0.f); v3 = fmaxf(v3, 0.f);
      }
      if (RESID) {
        short4v rv = *(const short4v*)&resid[base];
        v0 += bf2f((ushort)rv[0]); v1 += bf2f((ushort)rv[1]);
        v2 += bf2f((ushort)rv[2]); v3 += bf2f((ushort)rv[3]);
      }
      short4v o;
      o[0] = (short)f2bf(v0); o[1] = (short)f2bf(v1);
      o[2] = (short)f2bf(v2); o[3] = (short)f2bf(v3);
      *(short4v*)&out[base] = o;
    }
  }
}

// ---------------------------------------------------------------------------
// Fused out-conv (64->225 pad 256) + abs-softmax + 15x15 kernel-conv.
// Block 256 = 4 waves; wave w = oc [64w, 64w+64) x 64 px (4mt x 4nt).
// Weights streamed per-ks in 16KB LDS chunks, double-buffered (18 chunks).
// |core+bias| exchanged via fp16 LDS aliasing wLds+xs; consumer = R3's.
// ---------------------------------------------------------------------------
__global__ __launch_bounds__(256, 2) void out_kc_k(
    const ushort* __restrict__ x, const ushort* __restrict__ wf,
    const float* __restrict__ b_out, const float* __restrict__ data,
    float* __restrict__ pred) {
  constexpr int CHW = 16 * 64 * 8;  // halfwords per 1-ks chunk (16KB)
  // union: [ wLds 2x16KB | xs 25.6KB ] aliased by coreSh [64][264] fp16
  __shared__ __align__(16) char uni[2 * CHW * 2 + 1600 * 16];
  __shared__ float dsh[3][15][78];
  __shared__ float bsh[256];
  ushort* wLds = (ushort*)uni;
  ushort* xs = (ushort*)(uni + 2 * CHW * 2);
  _Float16* coreSh = (_Float16*)uni;  // [64 px][264]

  const int tid = threadIdx.x;
  const int wave = tid >> 6, lane = tid & 63;
  const int quad = lane >> 4, l15 = lane & 15;
  const int x0 = blockIdx.x * 64, y = blockIdx.y, b = blockIdx.z;

  // stage x tile: 3 padded rows y..y+2, cols x0..x0+65 (swizzled)
  for (int s0 = wave * 64; s0 < 3 * 528; s0 += 256) {
    int s = s0 + lane;
    int row = s / 528;
    int r = s - row * 528;
    int col = r >> 3;
    int chunk = (r & 7) ^ (col & 7);
    const ushort* g = x + ((size_t)b * PP + (size_t)(y + row) * PW +
                           (x0 + col)) * 64 + chunk * 8;
    GLD_LDS(g, &xs[(size_t)s0 * 8]);
  }
  // stage weight chunk 0
#pragma unroll
  for (int r = 0; r < 4; ++r) {
    int s0 = r * 256 + wave * 64;
    GLD_LDS(wf + (size_t)(s0 + lane) * 8, &wLds[s0 * 8]);
  }
  bsh[tid] = (tid < 225) ? b_out[tid] : 0.f;
  // stage data halo [3][15][78] fp32 (pad 7, zero-fill; data unpadded)
  for (int i = tid; i < 3 * 15 * 78; i += 256) {
    int ch = i / 1170;
    int rem = i - ch * 1170;
    int r = rem / 78;
    int cc = rem - r * 78;
    int gy = y - 7 + r, gx = x0 - 7 + cc;
    float v = 0.f;
    if ((unsigned)gy < (unsigned)HW && (unsigned)gx < (unsigned)HW)
      v = data[((b * 3 + ch) << 16) + (gy << 8) + gx];
    dsh[ch][r][cc] = v;
  }
  __syncthreads();

  f32x4 acc[4][4];
#pragma unroll
  for (int mt = 0; mt < 4; ++mt)
#pragma unroll
    for (int nt = 0; nt < 4; ++nt)
#pragma unroll
      for (int r = 0; r < 4; ++r) acc[mt][nt][r] = 0.f;

#pragma unroll
  for (int ks = 0; ks < 18; ++ks) {
    if (ks + 1 < 18) {  // DMA next weight chunk
      const ushort* src = wf + (size_t)(ks + 1) * CHW;
      ushort* dst = &wLds[((ks + 1) & 1) * CHW];
#pragma unroll
      for (int r = 0; r < 4; ++r) {
        int s0 = r * 256 + wave * 64;
        GLD_LDS(src + (size_t)(s0 + lane) * 8, dst + s0 * 8);
      }
    }
    const ushort* wb = &wLds[(ks & 1) * CHW];
    short8 A[4], B[4];
#pragma unroll
    for (int mt = 0; mt < 4; ++mt)
      A[mt] = *(const short8*)&wb[((wave * 4 + mt) * 64 + lane) * 8];
    int t = ks >> 1;
    int dy = t / 3, dx = t - (t / 3) * 3;
    int chunk = ((ks & 1) << 2) + quad;
#pragma unroll
    for (int nt = 0; nt < 4; ++nt) {
      int c = nt * 16 + l15 + dx;
      int slot = dy * 528 + c * 8 + (chunk ^ (c & 7));
      B[nt] = *(const short8*)&xs[(size_t)slot * 8];
    }
#pragma unroll
    for (int nt = 0; nt < 4; ++nt)
#pragma unroll
      for (int mt = 0; mt < 4; ++mt)
        acc[mt][nt] = __builtin_amdgcn_mfma_f32_16x16x32_bf16(
            A[mt], B[nt], acc[mt][nt], 0, 0, 0);
    __syncthreads();  // next-chunk DMA drained; safe to overwrite other buf
  }

  // producer: |core + bias| (masked -> -1e4) as fp16, row stride 264
#pragma unroll
  for (int mt = 0; mt < 4; ++mt) {
    int c0 = wave * 64 + mt * 16 + quad * 4;
#pragma unroll
    for (int nt = 0; nt < 4; ++nt) {
      int px = nt * 16 + l15;
      h4 hv;
#pragma unroll
      for (int r = 0; r < 4; ++r) {
        int c = c0 + r;
        float a = acc[mt][nt][r] + bsh[c];
        a = (c < 225) ? fabsf(a) : -1e4f;
        hv[r] = (_Float16)a;
      }
      *(h4*)&coreSh[px * 264 + c0] = hv;
    }
  }
  __syncthreads();

  // consumer: lane -> (px = wave*16+l15, channel quarter = quad)
  const int px = wave * 16 + l15;
  const int cbase = quad * 64;
  h8 vals[8];
#pragma unroll
  for (int v = 0; v < 8; ++v)
    vals[v] = *(h8*)&coreSh[px * 264 + cbase + v * 8];

  float m = 0.f;  // |core| >= 0; masked entries negative
#pragma unroll
  for (int v = 0; v < 8; ++v)
#pragma unroll
    for (int z = 0; z < 8; ++z) m = fmaxf(m, (float)vals[v][z]);
  m = fmaxf(m, __shfl_xor(m, 16));
  m = fmaxf(m, __shfl_xor(m, 32));

  float l = 0.f, p0 = 0.f, p1 = 0.f, p2 = 0.f;
#pragma unroll
  for (int v = 0; v < 8; ++v)
#pragma unroll
    for (int z = 0; z < 8; ++z) {
      int c = cbase + v * 8 + z;
      float a = (float)vals[v][z];
      float e = __expf(a - m);  // masked channels underflow to 0
      l += e;
      if (c < 225) {
        int di = (int)(((unsigned)c * 34953u) >> 19);  // c/15 exact
        int dj = c - di * 15;
        p0 += e * dsh[0][di][px + dj];
        p1 += e * dsh[1][di][px + dj];
        p2 += e * dsh[2][di][px + dj];
      }
    }
  l += __shfl_xor(l, 16);  l += __shfl_xor(l, 32);
  p0 += __shfl_xor(p0, 16); p0 += __shfl_xor(p0, 32);
  p1 += __shfl_xor(p1, 16); p1 += __shfl_xor(p1, 32);
  p2 += __shfl_xor(p2, 16); p2 += __shfl_xor(p2, 32);

  if (quad == 0) {
    float inv = 1.f / l;
    int pix = (y << 8) + x0 + px;
    pred[((b * 3 + 0) << 16) + pix] = p0 * inv;
    pred[((b * 3 + 1) << 16) + pix] = p1 * inv;
    pred[((b * 3 + 2) << 16) + pix] = p2 * inv;
  }
}

// ---------------------------------------------------------------------------
// data -> d_out[0 : 786432] verbatim copy (float4)
// ---------------------------------------------------------------------------
__global__ void copy_k(const float4* __restrict__ src, float4* __restrict__ dst,
                       int n4) {
  int i = blockIdx.x * blockDim.x + threadIdx.x;
  if (i < n4) dst[i] = src[i];
}

extern "C" void kernel_launch(void* const* d_in, const int* in_sizes, int n_in,
                              void* d_out, int out_size, void* d_ws,
                              size_t ws_size, hipStream_t stream) {
  const float* data_with_est = (const float*)d_in[0];
  const float* data = (const float*)d_in[1];
  const float* w_first = (const float*)d_in[2];
  const float* b_first = (const float*)d_in[3];
  const float* wa[3] = {(const float*)d_in[4], (const float*)d_in[8],
                        (const float*)d_in[12]};
  const float* ba[3] = {(const float*)d_in[5], (const float*)d_in[9],
                        (const float*)d_in[13]};
  const float* wb[3] = {(const float*)d_in[6], (const float*)d_in[10],
                        (const float*)d_in[14]};
  const float* bb[3] = {(const float*)d_in[7], (const float*)d_in[11],
                        (const float*)d_in[15]};
  const float* w_out = (const float*)d_in[16];
  const float* b_out = (const float*)d_in[17];

  float* out = (float*)d_out;
  float* pred = out + 4 * 3 * NPIX;

  // workspace layout (ushort units) — DMA overshoot of each buffer must land
  // in the next mapped region; trailing pad absorbs the last buffer's.
  ushort* x = (ushort*)d_ws;                 // 4*PP*64
  ushort* y = x + (size_t)4 * PP * 64;       // 4*PP*64
  ushort* xp = y + (size_t)4 * PP * 64;      // 4*PP*8
  ushort* Wp1 = xp + (size_t)4 * PP * 8;     // 6144   (first conv, frag order)
  ushort* Wpr = Wp1 + 6144;                  // 6*36864 (res convs, frag order)
  ushort* Wpo = Wpr + 6 * 36864;             // 147456 (out conv, frag order)
  // + implicit 4KB pad requirement after Wpo (ws_size slack)

  // packs + halo zeroing
  pack_in_k<<<1024, 256, 0, stream>>>(data_with_est, xp);
  zero_halo_k<<<17, 256, 0, stream>>>(x, y, xp);
  pack_wfrag_k<<<24, 256, 0, stream>>>(w_first, Wp1, 64, 6, 8, 4, 6144);
  for (int i = 0; i < 3; ++i) {
    pack_wfrag_k<<<144, 256, 0, stream>>>(wa[i], Wpr + (2 * i) * 36864, 64, 64,
                                          64, 4, 36864);
    pack_wfrag_k<<<144, 256, 0, stream>>>(wb[i], Wpr + (2 * i + 1) * 36864, 64,
                                          64, 64, 4, 36864);
  }
  pack_wfrag_k<<<576, 256, 0, stream>>>(w_out, Wpo, 225, 64, 64, 16, 147456);

  dim3 cgrid(4, 64, 4), cblk(256);
  // first conv 6->64 (C padded to 8, K padded to 96)
  conv_mfma_k<8, 3, false, false>
      <<<cgrid, cblk, 0, stream>>>(xp, Wp1, b_first, nullptr, x);
  // 3 residual blocks
  for (int i = 0; i < 3; ++i) {
    conv_mfma_k<64, 18, true, false><<<cgrid, cblk, 0, stream>>>(
        x, Wpr + (2 * i) * 36864, ba[i], nullptr, y);
    conv_mfma_k<64, 18, false, true><<<cgrid, cblk, 0, stream>>>(
        y, Wpr + (2 * i + 1) * 36864, bb[i], x, x);
  }
  // fused out-conv + softmax + kernel-conv
  out_kc_k<<<dim3(4, HW, 4), 256, 0, stream>>>(x, Wpo, b_out, data, pred);
  // data passthrough
  int n4 = 4 * 3 * NPIX / 4;
  copy_k<<<(n4 + 255) / 256, 256, 0, stream>>>((const float4*)data,
                                               (float4*)out, n4);
}